// Round 1
// baseline (922.421 us; speedup 1.0000x reference)
//
#include <hip/hip_runtime.h>
#include <math.h>

#define BB 8
#define SS 2048
#define DD 64
#define PAIR_BASE 20000
#define CEPS 1e-8f

// Workspace layout: accumulators + mask-dtype flag + per-row prior ranges.
struct Ws {
    double numer;          // offset 0
    double denom;          // offset 8
    int    byteMode;       // offset 16: 1 if masks are 1-byte bools, 0 if int32
    int    pad0;
    long long pad1;        // ranges start at offset 32 (16B aligned)
    int2   ranges[BB * SS];
};

__device__ __forceinline__ int lower_bound_dev(const int* __restrict__ a, int n, int x) {
    int lo = 0, hi = n;
    while (lo < hi) {
        int mid = (lo + hi) >> 1;
        if (a[mid] < x) lo = mid + 1; else hi = mid;
    }
    return lo;
}

__device__ __forceinline__ bool read_mask(const void* p, int i, int byteMode) {
    if (byteMode) return ((const unsigned char*)p)[i] != 0;
    return ((const int*)p)[i] != 0;
}

// Kernel 0: detect mask dtype (bool-bytes vs int32) and zero accumulators.
// Reads first 16KB of tf_mask = 4096 words; safe in both layouts
// (byte layout buffer is exactly 16384 B). Random 0/1 int32 words are all
// <=1; byte-packed bools whp produce a word >1.
__global__ void detect_and_init(const void* __restrict__ tf_raw, Ws* __restrict__ ws) {
    __shared__ int bad;
    if (threadIdx.x == 0) bad = 0;
    __syncthreads();
    const unsigned int* w = (const unsigned int*)tf_raw;
    int localbad = 0;
    for (int i = threadIdx.x; i < 4096; i += 256) {
        if (w[i] > 1u) localbad = 1;
    }
    if (localbad) atomicOr(&bad, 1);
    __syncthreads();
    if (threadIdx.x == 0) {
        ws->numer = 0.0;
        ws->denom = 0.0;
        ws->byteMode = bad;
    }
}

// Kernel 1: per-(b,s) row range into sorted prior keys:
// keys for source id fall in [id*20000, (id+1)*20000).
__global__ void row_ranges_kernel(const int* __restrict__ ids,
                                  const int* __restrict__ prior, int M,
                                  Ws* __restrict__ ws) {
    int i = blockIdx.x * blockDim.x + threadIdx.x;
    if (i < BB * SS) {
        int id = ids[i];
        int base = id * PAIR_BASE;
        int lo = lower_bound_dev(prior, M, base);
        int hi = lower_bound_dev(prior, M, base + PAIR_BASE);
        ws->ranges[i] = make_int2(lo, hi);
    }
}

// Kernel 2: main. 64x64 output tile per 256-thread block, K=64 fully in LDS.
// Each thread computes a 4x4 patch, applies supervise mask, clip, log terms,
// positive detection via the precomputed narrow prior range.
__global__ __launch_bounds__(256) void prior_loss_main(
    const int* __restrict__ ids,
    const void* __restrict__ tf_raw,
    const void* __restrict__ act_raw,
    const int* __restrict__ prior,
    const float* __restrict__ u,
    const float* __restrict__ v,
    Ws* __restrict__ ws)
{
    __shared__ float Ut[64][68];   // +4 pad: float4-aligned rows, bank-spread
    __shared__ float Vt[64][68];

    const int b  = blockIdx.z;
    const int s0 = blockIdx.y * 64;
    const int t0 = blockIdx.x * 64;
    const int tid = threadIdx.x;
    const int byteMode = ws->byteMode;

    const float* ubase = u + ((size_t)(b * SS + s0)) * DD;
    const float* vbase = v + ((size_t)(b * SS + t0)) * DD;
    #pragma unroll
    for (int it = 0; it < 4; ++it) {
        int idx = tid + it * 256;      // 0..1023
        int r = idx >> 4;              // row 0..63
        int c = idx & 15;              // float4 index 0..15
        *(float4*)&Ut[r][c * 4] = *(const float4*)(ubase + r * 64 + c * 4);
        *(float4*)&Vt[r][c * 4] = *(const float4*)(vbase + r * 64 + c * 4);
    }
    __syncthreads();

    const int tc = tid & 15, tr = tid >> 4;   // 16x16 thread grid
    const int r0 = tr * 4, c0 = tc * 4;
    float acc[4][4] = {};

    #pragma unroll
    for (int k = 0; k < 64; k += 4) {
        float4 Ar[4], Br[4];
        Ar[0] = *(const float4*)&Ut[r0 + 0][k];
        Ar[1] = *(const float4*)&Ut[r0 + 1][k];
        Ar[2] = *(const float4*)&Ut[r0 + 2][k];
        Ar[3] = *(const float4*)&Ut[r0 + 3][k];
        Br[0] = *(const float4*)&Vt[c0 + 0][k];
        Br[1] = *(const float4*)&Vt[c0 + 1][k];
        Br[2] = *(const float4*)&Vt[c0 + 2][k];
        Br[3] = *(const float4*)&Vt[c0 + 3][k];
        #pragma unroll
        for (int i = 0; i < 4; ++i) {
            #pragma unroll
            for (int j = 0; j < 4; ++j) {
                acc[i][j] += Ar[i].x * Br[j].x;
                acc[i][j] += Ar[i].y * Br[j].y;
                acc[i][j] += Ar[i].z * Br[j].z;
                acc[i][j] += Ar[i].w * Br[j].w;
            }
        }
    }

    // Epilogue: masks, ids, row ranges for this thread's 4 rows / 4 cols.
    const int g_s = b * SS + s0 + r0;
    const int g_t = b * SS + t0 + c0;
    bool tfr[4], actc[4];
    int rid[4], cid[4];
    int2 rg[4];
    #pragma unroll
    for (int i = 0; i < 4; ++i) {
        tfr[i]  = read_mask(tf_raw,  g_s + i, byteMode);
        rg[i]   = ws->ranges[g_s + i];
        rid[i]  = ids[g_s + i];
        actc[i] = read_mask(act_raw, g_t + i, byteMode);
        cid[i]  = ids[g_t + i];
    }

    float lsum = 0.f;
    int cnt = 0;
    #pragma unroll
    for (int i = 0; i < 4; ++i) {
        if (!tfr[i]) continue;
        const int base_key = rid[i] * PAIR_BASE;
        #pragma unroll
        for (int j = 0; j < 4; ++j) {
            if (!actc[j]) continue;
            cnt++;
            float p = fminf(fmaxf(acc[i][j], CEPS), 1.0f - CEPS);
            int key = base_key + cid[j];
            int lo = rg[i].x, hi = rg[i].y;
            const int hi0 = hi;
            while (lo < hi) {
                int mid = (lo + hi) >> 1;
                if (prior[mid] < key) lo = mid + 1; else hi = mid;
            }
            bool pos = (lo < hi0) && (prior[lo] == key);
            lsum += pos ? (-logf(p)) : (-log1pf(-p));
        }
    }

    // Block reduction (reuse LDS tiles as scratch).
    __syncthreads();
    float* redf = &Ut[0][0];
    int*   redi = (int*)&Vt[0][0];
    redf[tid] = lsum;
    redi[tid] = cnt;
    __syncthreads();
    #pragma unroll
    for (int ofs = 128; ofs > 0; ofs >>= 1) {
        if (tid < ofs) {
            redf[tid] += redf[tid + ofs];
            redi[tid] += redi[tid + ofs];
        }
        __syncthreads();
    }
    if (tid == 0) {
        atomicAdd(&ws->numer, (double)redf[0]);
        atomicAdd(&ws->denom, (double)redi[0]);
    }
}

// Kernel 3: finalize.
__global__ void finalize_kernel(const Ws* __restrict__ ws, float* __restrict__ out) {
    out[0] = (float)(ws->numer / (ws->denom + 1e-8));
}

extern "C" void kernel_launch(void* const* d_in, const int* in_sizes, int n_in,
                              void* d_out, int out_size, void* d_ws, size_t ws_size,
                              hipStream_t stream) {
    (void)n_in; (void)out_size; (void)ws_size;
    const int*   ids   = (const int*)d_in[0];
    const void*  tf    = d_in[1];
    const void*  act   = d_in[2];
    const int*   prior = (const int*)d_in[3];
    const int    M     = in_sizes[3];
    const float* u     = (const float*)d_in[4];
    const float* v     = (const float*)d_in[5];
    Ws* ws = (Ws*)d_ws;
    float* out = (float*)d_out;

    detect_and_init<<<1, 256, 0, stream>>>(tf, ws);
    row_ranges_kernel<<<(BB * SS + 255) / 256, 256, 0, stream>>>(ids, prior, M, ws);
    dim3 grid(SS / 64, SS / 64, BB);
    prior_loss_main<<<grid, 256, 0, stream>>>(ids, tf, act, prior, u, v, ws);
    finalize_kernel<<<1, 1, 0, stream>>>(ws, out);
}

// Round 2
// 280.402 us; speedup vs baseline: 3.2896x; 3.2896x over previous
//
#include <hip/hip_runtime.h>
#include <math.h>

#define BB 8
#define SS 2048
#define DD 64
#define PAIR_BASE 20000
#define CEPS 1e-8f

typedef __bf16 bf16x8 __attribute__((ext_vector_type(8)));
typedef __bf16 bf16x4 __attribute__((ext_vector_type(4)));
typedef float  f32x4  __attribute__((ext_vector_type(4)));

// Workspace layout: accumulators + mask-dtype flag + per-row prior ranges.
struct Ws {
    double numer;          // offset 0
    double denom;          // offset 8
    int    byteMode;       // offset 16: 1 if masks are 1-byte bools, 0 if int32
    int    pad0;
    long long pad1;        // ranges start at offset 32 (16B aligned)
    int2   ranges[BB * SS];
};

__device__ __forceinline__ int lower_bound_dev(const int* __restrict__ a, int n, int x) {
    int lo = 0, hi = n;
    while (lo < hi) {
        int mid = (lo + hi) >> 1;
        if (a[mid] < x) lo = mid + 1; else hi = mid;
    }
    return lo;
}

__device__ __forceinline__ bool read_mask(const void* p, int i, int byteMode) {
    if (byteMode) return ((const unsigned char*)p)[i] != 0;
    return ((const int*)p)[i] != 0;
}

// Kernel 0: detect mask dtype (bool-bytes vs int32) and zero accumulators.
__global__ void detect_and_init(const void* __restrict__ tf_raw, Ws* __restrict__ ws) {
    __shared__ int bad;
    if (threadIdx.x == 0) bad = 0;
    __syncthreads();
    const unsigned int* w = (const unsigned int*)tf_raw;
    int localbad = 0;
    for (int i = threadIdx.x; i < 4096; i += 256) {
        if (w[i] > 1u) localbad = 1;
    }
    if (localbad) atomicOr(&bad, 1);
    __syncthreads();
    if (threadIdx.x == 0) {
        ws->numer = 0.0;
        ws->denom = 0.0;
        ws->byteMode = bad;
    }
}

// Kernel 1: per-(b,s) range into sorted prior keys: keys for src id lie in
// [id*20000, (id+1)*20000) — avg 10 elements.
__global__ void row_ranges_kernel(const int* __restrict__ ids,
                                  const int* __restrict__ prior, int M,
                                  Ws* __restrict__ ws) {
    int i = blockIdx.x * blockDim.x + threadIdx.x;
    if (i < BB * SS) {
        int id = ids[i];
        int base = id * PAIR_BASE;
        int lo = lower_bound_dev(prior, M, base);
        int hi = lower_bound_dev(prior, M, base + PAIR_BASE);
        ws->ranges[i] = make_int2(lo, hi);
    }
}

// Kernel 2: MFMA main. 128x128 tile per 256-thread block (4 waves, each a
// 64x64 quadrant = 4x4 tiles of 16x16x32 bf16 MFMA, K=64 in one LDS pass).
// Row stride 72 bf16 (144 B): fragment-read bank step = 4 words -> <=2-way.
__global__ __launch_bounds__(256) void prior_loss_main(
    const int* __restrict__ ids,
    const void* __restrict__ tf_raw,
    const void* __restrict__ act_raw,
    const int* __restrict__ prior,
    const float* __restrict__ u,
    const float* __restrict__ v,
    Ws* __restrict__ ws)
{
    __shared__ __align__(16) __bf16 Ulds[128 * 72];
    __shared__ __align__(16) __bf16 Vlds[128 * 72];
    __shared__ int srow_tf[128], srow_id[128], srow_lo[128], srow_hi[128];
    __shared__ int scol_act[128], scol_id[128];
    __shared__ float wsumS[4];
    __shared__ int   wcntS[4];

    const int b  = blockIdx.z;
    const int s0 = blockIdx.y * 128;
    const int t0 = blockIdx.x * 128;
    const int tid = threadIdx.x;
    const int byteMode = ws->byteMode;

    // ---- Stage U,V tiles (fp32 -> bf16) into LDS ----
    const float* ubase = u + ((size_t)(b * SS + s0)) * DD;
    const float* vbase = v + ((size_t)(b * SS + t0)) * DD;
    #pragma unroll
    for (int it = 0; it < 8; ++it) {
        int li = tid + it * 256;        // 0..2047
        int r  = li >> 4;               // row 0..127
        int c4 = li & 15;               // float4 index 0..15
        float4 fu = *(const float4*)(ubase + r * DD + c4 * 4);
        float4 fv = *(const float4*)(vbase + r * DD + c4 * 4);
        bf16x4 hu = { (__bf16)fu.x, (__bf16)fu.y, (__bf16)fu.z, (__bf16)fu.w };
        bf16x4 hv = { (__bf16)fv.x, (__bf16)fv.y, (__bf16)fv.z, (__bf16)fv.w };
        *(bf16x4*)&Ulds[r * 72 + c4 * 4] = hu;
        *(bf16x4*)&Vlds[r * 72 + c4 * 4] = hv;
    }
    // ---- Stage per-row / per-col metadata ----
    if (tid < 128) {
        int gs = b * SS + s0 + tid;
        srow_tf[tid] = read_mask(tf_raw, gs, byteMode) ? 1 : 0;
        srow_id[tid] = ids[gs];
        int2 rr = ws->ranges[gs];
        srow_lo[tid] = rr.x;
        srow_hi[tid] = rr.y;
    } else {
        int t = tid - 128;
        int gt = b * SS + t0 + t;
        scol_act[t] = read_mask(act_raw, gt, byteMode) ? 1 : 0;
        scol_id[t]  = ids[gt];
    }
    __syncthreads();

    // ---- MFMA: wave quadrant ----
    const int w    = tid >> 6;
    const int lane = tid & 63;
    const int quad = lane >> 4;
    const int l15  = lane & 15;
    const int wm0  = (w >> 1) * 64;     // quadrant row base (0 or 64)
    const int wn0  = (w & 1) * 64;      // quadrant col base (0 or 64)

    f32x4 acc[4][4];
    #pragma unroll
    for (int i = 0; i < 4; ++i)
        #pragma unroll
        for (int j = 0; j < 4; ++j)
            acc[i][j] = (f32x4){0.f, 0.f, 0.f, 0.f};

    #pragma unroll
    for (int kh = 0; kh < 2; ++kh) {
        const int kcol = kh * 32 + quad * 8;
        bf16x8 af[4], bf[4];
        #pragma unroll
        for (int ti = 0; ti < 4; ++ti)
            af[ti] = *(const bf16x8*)&Ulds[(wm0 + ti * 16 + l15) * 72 + kcol];
        #pragma unroll
        for (int tj = 0; tj < 4; ++tj)
            bf[tj] = *(const bf16x8*)&Vlds[(wn0 + tj * 16 + l15) * 72 + kcol];
        #pragma unroll
        for (int ti = 0; ti < 4; ++ti)
            #pragma unroll
            for (int tj = 0; tj < 4; ++tj)
                acc[ti][tj] = __builtin_amdgcn_mfma_f32_16x16x32_bf16(
                    af[ti], bf[tj], acc[ti][tj], 0, 0, 0);
    }

    // ---- Epilogue: mask, clip, positive-search, log terms ----
    // C/D layout (m89/m91): col = lane&15, row = quad*4 + reg.
    float lsum = 0.f;
    int cnt = 0;
    #pragma unroll
    for (int ti = 0; ti < 4; ++ti) {
        #pragma unroll
        for (int r = 0; r < 4; ++r) {
            const int mloc = wm0 + ti * 16 + quad * 4 + r;
            if (!srow_tf[mloc]) continue;
            const int basekey = srow_id[mloc] * PAIR_BASE;
            const int rlo = srow_lo[mloc], rhi = srow_hi[mloc];
            #pragma unroll
            for (int tj = 0; tj < 4; ++tj) {
                const int nloc = wn0 + tj * 16 + l15;
                if (!scol_act[nloc]) continue;
                cnt++;
                float p = fminf(fmaxf(acc[ti][tj][r], CEPS), 1.0f - CEPS);
                const int key = basekey + scol_id[nloc];
                int lo = rlo, hi = rhi;
                while (lo < hi) {
                    int mid = (lo + hi) >> 1;
                    if (prior[mid] < key) lo = mid + 1; else hi = mid;
                }
                const bool pos = (lo < rhi) && (prior[lo] == key);
                lsum += pos ? (-logf(p)) : (-log1pf(-p));
            }
        }
    }

    // ---- Reduction: wave shuffle -> LDS -> block -> global atomics ----
    #pragma unroll
    for (int o = 32; o > 0; o >>= 1) {
        lsum += __shfl_down(lsum, o, 64);
        cnt  += __shfl_down(cnt,  o, 64);
    }
    if (lane == 0) { wsumS[w] = lsum; wcntS[w] = cnt; }
    __syncthreads();
    if (tid == 0) {
        double ns = (double)wsumS[0] + wsumS[1] + wsumS[2] + wsumS[3];
        double nc = (double)(wcntS[0] + wcntS[1] + wcntS[2] + wcntS[3]);
        atomicAdd(&ws->numer, ns);
        atomicAdd(&ws->denom, nc);
    }
}

// Kernel 3: finalize.
__global__ void finalize_kernel(const Ws* __restrict__ ws, float* __restrict__ out) {
    out[0] = (float)(ws->numer / (ws->denom + 1e-8));
}

extern "C" void kernel_launch(void* const* d_in, const int* in_sizes, int n_in,
                              void* d_out, int out_size, void* d_ws, size_t ws_size,
                              hipStream_t stream) {
    (void)n_in; (void)out_size; (void)ws_size;
    const int*   ids   = (const int*)d_in[0];
    const void*  tf    = d_in[1];
    const void*  act   = d_in[2];
    const int*   prior = (const int*)d_in[3];
    const int    M     = in_sizes[3];
    const float* u     = (const float*)d_in[4];
    const float* v     = (const float*)d_in[5];
    Ws* ws = (Ws*)d_ws;
    float* out = (float*)d_out;

    detect_and_init<<<1, 256, 0, stream>>>(tf, ws);
    row_ranges_kernel<<<(BB * SS + 255) / 256, 256, 0, stream>>>(ids, prior, M, ws);
    dim3 grid(SS / 128, SS / 128, BB);
    prior_loss_main<<<grid, 256, 0, stream>>>(ids, tf, act, prior, u, v, ws);
    finalize_kernel<<<1, 1, 0, stream>>>(ws, out);
}

// Round 3
// 234.549 us; speedup vs baseline: 3.9327x; 1.1955x over previous
//
#include <hip/hip_runtime.h>
#include <math.h>

#define BB 8
#define SS 2048
#define DD 64
#define PAIR_BASE 20000
#define CEPS 1e-8f
#define NROWS (BB * SS)

typedef __bf16 bf16x8 __attribute__((ext_vector_type(8)));
typedef __bf16 bf16x4 __attribute__((ext_vector_type(4)));
typedef float  f32x4  __attribute__((ext_vector_type(4)));

// Workspace: header + per-row prior ranges + per-batch id-sorted column keys.
struct Ws {
    double numer;                 // 0
    double denom;                 // 8
    int    byteMode;              // 16
    int    pad0;
    int2   ranges[NROWS];         // 128 KB
    unsigned int sorted[NROWS];   // 64 KB: (id<<11)|t, sorted per batch
};

__device__ __forceinline__ bool read_mask(const void* p, int i, int byteMode) {
    if (byteMode) return ((const unsigned char*)p)[i] != 0;
    return ((const int*)p)[i] != 0;
}

__device__ __forceinline__ int lower_bound_dev(const int* __restrict__ a, int n, int x) {
    int lo = 0, hi = n;
    while (lo < hi) {
        int mid = (lo + hi) >> 1;
        if (a[mid] < x) lo = mid + 1; else hi = mid;
    }
    return lo;
}

// Kernel 0: detect mask dtype, zero numer, closed-form denom =
// sum_b (#tf_b * #act_b).  Single block.
__global__ void init_all(const void* __restrict__ tf_raw,
                         const void* __restrict__ act_raw,
                         Ws* __restrict__ ws) {
    __shared__ int bad;
    __shared__ int tfc[BB], acc_[BB];
    if (threadIdx.x == 0) bad = 0;
    if (threadIdx.x < BB) { tfc[threadIdx.x] = 0; acc_[threadIdx.x] = 0; }
    __syncthreads();
    // First 16 KB of tf buffer is valid in both layouts (byte layout = 16384 B).
    const unsigned int* w = (const unsigned int*)tf_raw;
    int lb = 0;
    for (int i = threadIdx.x; i < 4096; i += 256)
        if (w[i] > 1u) lb = 1;
    if (lb) atomicOr(&bad, 1);
    __syncthreads();
    const int bm = bad;
    for (int i = threadIdx.x; i < NROWS; i += 256) {
        int b = i >> 11;
        if (read_mask(tf_raw,  i, bm)) atomicAdd(&tfc[b], 1);
        if (read_mask(act_raw, i, bm)) atomicAdd(&acc_[b], 1);
    }
    __syncthreads();
    if (threadIdx.x == 0) {
        double d = 0.0;
        for (int b = 0; b < BB; ++b) d += (double)tfc[b] * (double)acc_[b];
        ws->numer = 0.0;
        ws->denom = d;
        ws->byteMode = bm;
    }
}

// Kernel 1: per-(b,s) range into sorted prior keys.
__global__ void row_ranges_kernel(const int* __restrict__ ids,
                                  const int* __restrict__ prior, int M,
                                  Ws* __restrict__ ws) {
    int i = blockIdx.x * blockDim.x + threadIdx.x;
    if (i < NROWS) {
        int id = ids[i];
        int base = id * PAIR_BASE;
        int lo = lower_bound_dev(prior, M, base);
        int hi = lower_bound_dev(prior, M, base + PAIR_BASE);
        ws->ranges[i] = make_int2(lo, hi);
    }
}

// Kernel 2: per-batch bitonic sort of keys (id<<11)|t.  One block per batch.
__global__ __launch_bounds__(1024) void sort_ids_kernel(const int* __restrict__ ids,
                                                        Ws* __restrict__ ws) {
    __shared__ unsigned int arr[SS];
    const int b = blockIdx.x;
    for (int i = threadIdx.x; i < SS; i += 1024)
        arr[i] = ((unsigned int)ids[b * SS + i] << 11) | (unsigned int)i;
    __syncthreads();
    for (int k = 2; k <= SS; k <<= 1) {
        for (int j = k >> 1; j > 0; j >>= 1) {
            for (int t = threadIdx.x; t < SS; t += 1024) {
                int ixj = t ^ j;
                if (ixj > t) {
                    unsigned int a = arr[t], c = arr[ixj];
                    bool up = ((t & k) == 0);
                    if ((a > c) == up) { arr[t] = c; arr[ixj] = a; }
                }
            }
            __syncthreads();
        }
    }
    for (int i = threadIdx.x; i < SS; i += 1024)
        ws->sorted[b * SS + i] = arr[i];
}

// Kernel 3: MFMA main, uniform negative-term sum only (no searches).
// 128x128 tile per 256-thread block; epilogue is branchless:
//   lsum += tf(row) * act(col) * log(clamp(1-acc, eps, 1-eps));  numer -= lsum
__global__ __launch_bounds__(256) void prior_loss_main(
    const void* __restrict__ tf_raw,
    const void* __restrict__ act_raw,
    const float* __restrict__ u,
    const float* __restrict__ v,
    Ws* __restrict__ ws)
{
    __shared__ __align__(16) __bf16 Ulds[128 * 72];
    __shared__ __align__(16) __bf16 Vlds[128 * 72];
    __shared__ float srow_tff[128];
    __shared__ float scol_actf[128];
    __shared__ float wsumS[4];

    const int b  = blockIdx.z;
    const int s0 = blockIdx.y * 128;
    const int t0 = blockIdx.x * 128;
    const int tid = threadIdx.x;
    const int byteMode = ws->byteMode;

    // ---- Stage U,V tiles (fp32 -> bf16) into LDS ----
    const float* ubase = u + ((size_t)(b * SS + s0)) * DD;
    const float* vbase = v + ((size_t)(b * SS + t0)) * DD;
    #pragma unroll
    for (int it = 0; it < 8; ++it) {
        int li = tid + it * 256;
        int r  = li >> 4;
        int c4 = li & 15;
        float4 fu = *(const float4*)(ubase + r * DD + c4 * 4);
        float4 fv = *(const float4*)(vbase + r * DD + c4 * 4);
        bf16x4 hu = { (__bf16)fu.x, (__bf16)fu.y, (__bf16)fu.z, (__bf16)fu.w };
        bf16x4 hv = { (__bf16)fv.x, (__bf16)fv.y, (__bf16)fv.z, (__bf16)fv.w };
        *(bf16x4*)&Ulds[r * 72 + c4 * 4] = hu;
        *(bf16x4*)&Vlds[r * 72 + c4 * 4] = hv;
    }
    if (tid < 128) {
        srow_tff[tid] = read_mask(tf_raw, b * SS + s0 + tid, byteMode) ? 1.f : 0.f;
    } else {
        int t = tid - 128;
        scol_actf[t] = read_mask(act_raw, b * SS + t0 + t, byteMode) ? 1.f : 0.f;
    }
    __syncthreads();

    // ---- MFMA: wave quadrant (4x4 tiles of 16x16x32 bf16) ----
    const int w    = tid >> 6;
    const int lane = tid & 63;
    const int quad = lane >> 4;
    const int l15  = lane & 15;
    const int wm0  = (w >> 1) * 64;
    const int wn0  = (w & 1) * 64;

    f32x4 acc[4][4];
    #pragma unroll
    for (int i = 0; i < 4; ++i)
        #pragma unroll
        for (int j = 0; j < 4; ++j)
            acc[i][j] = (f32x4){0.f, 0.f, 0.f, 0.f};

    #pragma unroll
    for (int kh = 0; kh < 2; ++kh) {
        const int kcol = kh * 32 + quad * 8;
        bf16x8 af[4], bfr[4];
        #pragma unroll
        for (int ti = 0; ti < 4; ++ti)
            af[ti] = *(const bf16x8*)&Ulds[(wm0 + ti * 16 + l15) * 72 + kcol];
        #pragma unroll
        for (int tj = 0; tj < 4; ++tj)
            bfr[tj] = *(const bf16x8*)&Vlds[(wn0 + tj * 16 + l15) * 72 + kcol];
        #pragma unroll
        for (int ti = 0; ti < 4; ++ti)
            #pragma unroll
            for (int tj = 0; tj < 4; ++tj)
                acc[ti][tj] = __builtin_amdgcn_mfma_f32_16x16x32_bf16(
                    af[ti], bfr[tj], acc[ti][tj], 0, 0, 0);
    }

    // ---- Branchless epilogue.  C/D layout: col=lane&15, row=quad*4+reg. ----
    float actf4[4];
    #pragma unroll
    for (int tj = 0; tj < 4; ++tj) actf4[tj] = scol_actf[wn0 + tj * 16 + l15];

    float lsum = 0.f;
    #pragma unroll
    for (int ti = 0; ti < 4; ++ti) {
        #pragma unroll
        for (int r = 0; r < 4; ++r) {
            const int mloc = wm0 + ti * 16 + quad * 4 + r;
            const float tff = srow_tff[mloc];
            float rsum = 0.f;
            #pragma unroll
            for (int tj = 0; tj < 4; ++tj) {
                float q = 1.0f - acc[ti][tj][r];
                q = fminf(fmaxf(q, CEPS), 1.0f - CEPS);
                rsum += actf4[tj] * __logf(q);
            }
            lsum += tff * rsum;
        }
    }
    lsum = -lsum;

    #pragma unroll
    for (int o = 32; o > 0; o >>= 1)
        lsum += __shfl_down(lsum, o, 64);
    if (lane == 0) wsumS[w] = lsum;
    __syncthreads();
    if (tid == 0) {
        double ns = (double)wsumS[0] + wsumS[1] + wsumS[2] + wsumS[3];
        atomicAdd(&ws->numer, ns);
    }
}

// Kernel 4: sparse positive correction.  64 blocks; block = (batch, row-chunk).
// For each TF row, walk its ~10-key prior range, match target ids against the
// batch's sorted column keys (in LDS), and for supervised positives add
// (-log p + log q) with p recomputed from a bf16-faithful dot.
__global__ __launch_bounds__(256) void positives_kernel(
    const int* __restrict__ ids,
    const void* __restrict__ tf_raw,
    const void* __restrict__ act_raw,
    const int* __restrict__ prior,
    const float* __restrict__ u,
    const float* __restrict__ v,
    Ws* __restrict__ ws)
{
    __shared__ unsigned int skey[SS];
    __shared__ float wsumS[4];
    const int b     = blockIdx.x >> 3;
    const int chunk = blockIdx.x & 7;
    for (int i = threadIdx.x; i < SS; i += 256)
        skey[i] = ws->sorted[b * SS + i];
    __syncthreads();

    const int bm = ws->byteMode;
    const int s  = chunk * 256 + threadIdx.x;
    const int gi = b * SS + s;

    float corr = 0.f;
    if (read_mask(tf_raw, gi, bm)) {
        const int2 rg = ws->ranges[gi];
        const int base = ids[gi] * PAIR_BASE;
        const float* urow = u + (size_t)gi * DD;
        for (int m = rg.x; m < rg.y; ++m) {
            const int tgt = prior[m] - base;            // in [0, PAIR_BASE)
            const unsigned int target = (unsigned int)tgt << 11;
            int lo = 0, hi = SS;
            while (lo < hi) {
                int mid = (lo + hi) >> 1;
                if (skey[mid] < target) lo = mid + 1; else hi = mid;
            }
            while (lo < SS && (skey[lo] >> 11) == (unsigned int)tgt) {
                const int t = (int)(skey[lo] & 2047u);
                if (read_mask(act_raw, b * SS + t, bm)) {
                    const float* vrow = v + (size_t)(b * SS + t) * DD;
                    float dot = 0.f;
                    #pragma unroll
                    for (int k2 = 0; k2 < DD; ++k2)
                        dot += (float)(__bf16)urow[k2] * (float)(__bf16)vrow[k2];
                    float p = fminf(fmaxf(dot, CEPS), 1.0f - CEPS);
                    float q = fminf(fmaxf(1.0f - dot, CEPS), 1.0f - CEPS);
                    corr += -__logf(p) + __logf(q);
                }
                ++lo;
            }
        }
    }

    const int w = threadIdx.x >> 6, lane = threadIdx.x & 63;
    #pragma unroll
    for (int o = 32; o > 0; o >>= 1)
        corr += __shfl_down(corr, o, 64);
    if (lane == 0) wsumS[w] = corr;
    __syncthreads();
    if (threadIdx.x == 0) {
        double ns = (double)wsumS[0] + wsumS[1] + wsumS[2] + wsumS[3];
        atomicAdd(&ws->numer, ns);
    }
}

// Kernel 5: finalize.
__global__ void finalize_kernel(const Ws* __restrict__ ws, float* __restrict__ out) {
    out[0] = (float)(ws->numer / (ws->denom + 1e-8));
}

extern "C" void kernel_launch(void* const* d_in, const int* in_sizes, int n_in,
                              void* d_out, int out_size, void* d_ws, size_t ws_size,
                              hipStream_t stream) {
    (void)n_in; (void)out_size; (void)ws_size;
    const int*   ids   = (const int*)d_in[0];
    const void*  tf    = d_in[1];
    const void*  act   = d_in[2];
    const int*   prior = (const int*)d_in[3];
    const int    M     = in_sizes[3];
    const float* u     = (const float*)d_in[4];
    const float* v     = (const float*)d_in[5];
    Ws* ws = (Ws*)d_ws;
    float* out = (float*)d_out;

    init_all<<<1, 256, 0, stream>>>(tf, act, ws);
    row_ranges_kernel<<<(NROWS + 255) / 256, 256, 0, stream>>>(ids, prior, M, ws);
    sort_ids_kernel<<<BB, 1024, 0, stream>>>(ids, ws);
    dim3 grid(SS / 128, SS / 128, BB);
    prior_loss_main<<<grid, 256, 0, stream>>>(tf, act, u, v, ws);
    positives_kernel<<<64, 256, 0, stream>>>(ids, tf, act, prior, u, v, ws);
    finalize_kernel<<<1, 1, 0, stream>>>(ws, out);
}

// Round 4
// 194.053 us; speedup vs baseline: 4.7535x; 1.2087x over previous
//
#include <hip/hip_runtime.h>
#include <math.h>

#define BB 8
#define SS 2048
#define DD 64
#define PAIR_BASE 20000
#define CEPS 1e-8f
#define NROWS (BB * SS)
#define NBND (PAIR_BASE + 1)
#define MAIN_BLOCKS (16 * 16 * BB)   // 2048
#define POS_BLOCKS (NROWS / 4)       // 4096 (4 waves/block, 1 wave/row)

typedef __bf16 bf16x8 __attribute__((ext_vector_type(8)));
typedef __bf16 bf16x4 __attribute__((ext_vector_type(4)));
typedef float  f32x4  __attribute__((ext_vector_type(4)));

// Workspace (~170 KB): no global atomics anywhere — per-block partials.
struct Ws {
    int byteMode;
    int pad;
    int tfc[BB];
    int actc[BB];
    int bnd[NBND];                  // lower_bound(prior, id*20000) per id
    unsigned int sorted[NROWS];     // per batch: (id<<11)|t, bitonic-sorted
    float mpart[MAIN_BLOCKS];       // main-kernel per-block negative-term sums
    float ppart[POS_BLOCKS];        // positives per-block corrections
};

__device__ __forceinline__ bool read_mask(const void* p, int i, int byteMode) {
    if (byteMode) return ((const unsigned char*)p)[i] != 0;
    return ((const int*)p)[i] != 0;
}

// Kernel 0: detect mask dtype + per-batch tf/act counts (ballot/popc; each
// wave's 64 rows are batch-uniform since 2048 % 64 == 0).  Single block.
__global__ __launch_bounds__(256) void init_kernel(const void* __restrict__ tf_raw,
                                                   const void* __restrict__ act_raw,
                                                   Ws* __restrict__ ws) {
    __shared__ int bad;
    __shared__ int tf_l[BB], act_l[BB];
    const int tid = threadIdx.x;
    if (tid == 0) bad = 0;
    if (tid < BB) { tf_l[tid] = 0; act_l[tid] = 0; }
    __syncthreads();
    // First 16 KB of tf buffer is valid in both layouts (byte layout = 16 KB).
    const unsigned int* w = (const unsigned int*)tf_raw;
    int lb = 0;
    for (int i = tid; i < 4096; i += 256)
        if (w[i] > 1u) lb = 1;
    if (lb) atomicOr(&bad, 1);
    __syncthreads();
    const int bm = bad;
    const int lane = tid & 63;
    for (int i = tid; i < NROWS; i += 256) {
        const int b = i >> 11;                      // wave-uniform
        unsigned long long mt = __ballot(read_mask(tf_raw,  i, bm));
        unsigned long long ma = __ballot(read_mask(act_raw, i, bm));
        if (lane == 0) {
            atomicAdd(&tf_l[b],  __popcll(mt));
            atomicAdd(&act_l[b], __popcll(ma));
        }
    }
    __syncthreads();
    if (tid == 0) ws->byteMode = bm;
    if (tid < BB) { ws->tfc[tid] = tf_l[tid]; ws->actc[tid] = act_l[tid]; }
}

// Kernel 1: prior boundary table — bnd[id] = lower_bound(prior, id*20000).
__global__ void bnd_kernel(const int* __restrict__ prior, int M,
                           Ws* __restrict__ ws) {
    int i = blockIdx.x * blockDim.x + threadIdx.x;
    if (i < NBND) {
        const int x = i * PAIR_BASE;       // max 4.0e8 < INT_MAX
        int lo = 0, hi = M;
        while (lo < hi) {
            int mid = (lo + hi) >> 1;
            if (prior[mid] < x) lo = mid + 1; else hi = mid;
        }
        ws->bnd[i] = lo;
    }
}

// Kernel 2: per-batch bitonic sort of keys (id<<11)|t.  One block per batch.
__global__ __launch_bounds__(1024) void sort_ids_kernel(const int* __restrict__ ids,
                                                        Ws* __restrict__ ws) {
    __shared__ unsigned int arr[SS];
    const int b = blockIdx.x;
    for (int i = threadIdx.x; i < SS; i += 1024)
        arr[i] = ((unsigned int)ids[b * SS + i] << 11) | (unsigned int)i;
    __syncthreads();
    for (int k = 2; k <= SS; k <<= 1) {
        for (int j = k >> 1; j > 0; j >>= 1) {
            for (int t = threadIdx.x; t < SS; t += 1024) {
                int ixj = t ^ j;
                if (ixj > t) {
                    unsigned int a = arr[t], c = arr[ixj];
                    bool up = ((t & k) == 0);
                    if ((a > c) == up) { arr[t] = c; arr[ixj] = a; }
                }
            }
            __syncthreads();
        }
    }
    for (int i = threadIdx.x; i < SS; i += 1024)
        ws->sorted[b * SS + i] = arr[i];
}

// Kernel 3: MFMA main, uniform negative-term sum (branchless epilogue).
__global__ __launch_bounds__(256) void prior_loss_main(
    const void* __restrict__ tf_raw,
    const void* __restrict__ act_raw,
    const float* __restrict__ u,
    const float* __restrict__ v,
    Ws* __restrict__ ws)
{
    __shared__ __align__(16) __bf16 Ulds[128 * 72];
    __shared__ __align__(16) __bf16 Vlds[128 * 72];
    __shared__ float srow_tff[128];
    __shared__ float scol_actf[128];
    __shared__ float wsumS[4];

    const int b  = blockIdx.z;
    const int s0 = blockIdx.y * 128;
    const int t0 = blockIdx.x * 128;
    const int tid = threadIdx.x;
    const int byteMode = ws->byteMode;

    const float* ubase = u + ((size_t)(b * SS + s0)) * DD;
    const float* vbase = v + ((size_t)(b * SS + t0)) * DD;
    #pragma unroll
    for (int it = 0; it < 8; ++it) {
        int li = tid + it * 256;
        int r  = li >> 4;
        int c4 = li & 15;
        float4 fu = *(const float4*)(ubase + r * DD + c4 * 4);
        float4 fv = *(const float4*)(vbase + r * DD + c4 * 4);
        bf16x4 hu = { (__bf16)fu.x, (__bf16)fu.y, (__bf16)fu.z, (__bf16)fu.w };
        bf16x4 hv = { (__bf16)fv.x, (__bf16)fv.y, (__bf16)fv.z, (__bf16)fv.w };
        *(bf16x4*)&Ulds[r * 72 + c4 * 4] = hu;
        *(bf16x4*)&Vlds[r * 72 + c4 * 4] = hv;
    }
    if (tid < 128) {
        srow_tff[tid] = read_mask(tf_raw, b * SS + s0 + tid, byteMode) ? 1.f : 0.f;
    } else {
        int t = tid - 128;
        scol_actf[t] = read_mask(act_raw, b * SS + t0 + t, byteMode) ? 1.f : 0.f;
    }
    __syncthreads();

    const int w    = tid >> 6;
    const int lane = tid & 63;
    const int quad = lane >> 4;
    const int l15  = lane & 15;
    const int wm0  = (w >> 1) * 64;
    const int wn0  = (w & 1) * 64;

    f32x4 acc[4][4];
    #pragma unroll
    for (int i = 0; i < 4; ++i)
        #pragma unroll
        for (int j = 0; j < 4; ++j)
            acc[i][j] = (f32x4){0.f, 0.f, 0.f, 0.f};

    #pragma unroll
    for (int kh = 0; kh < 2; ++kh) {
        const int kcol = kh * 32 + quad * 8;
        bf16x8 af[4], bfr[4];
        #pragma unroll
        for (int ti = 0; ti < 4; ++ti)
            af[ti] = *(const bf16x8*)&Ulds[(wm0 + ti * 16 + l15) * 72 + kcol];
        #pragma unroll
        for (int tj = 0; tj < 4; ++tj)
            bfr[tj] = *(const bf16x8*)&Vlds[(wn0 + tj * 16 + l15) * 72 + kcol];
        #pragma unroll
        for (int ti = 0; ti < 4; ++ti)
            #pragma unroll
            for (int tj = 0; tj < 4; ++tj)
                acc[ti][tj] = __builtin_amdgcn_mfma_f32_16x16x32_bf16(
                    af[ti], bfr[tj], acc[ti][tj], 0, 0, 0);
    }

    // C/D layout: col = lane&15, row = quad*4 + reg.
    float actf4[4];
    #pragma unroll
    for (int tj = 0; tj < 4; ++tj) actf4[tj] = scol_actf[wn0 + tj * 16 + l15];

    float lsum = 0.f;
    #pragma unroll
    for (int ti = 0; ti < 4; ++ti) {
        #pragma unroll
        for (int r = 0; r < 4; ++r) {
            const int mloc = wm0 + ti * 16 + quad * 4 + r;
            const float tff = srow_tff[mloc];
            float rsum = 0.f;
            #pragma unroll
            for (int tj = 0; tj < 4; ++tj) {
                float q = 1.0f - acc[ti][tj][r];
                q = fminf(fmaxf(q, CEPS), 1.0f - CEPS);
                rsum += actf4[tj] * __logf(q);
            }
            lsum += tff * rsum;
        }
    }
    lsum = -lsum;

    #pragma unroll
    for (int o = 32; o > 0; o >>= 1)
        lsum += __shfl_down(lsum, o, 64);
    if (lane == 0) wsumS[w] = lsum;
    __syncthreads();
    if (tid == 0) {
        const int flat = (blockIdx.z * gridDim.y + blockIdx.y) * gridDim.x + blockIdx.x;
        ws->mpart[flat] = wsumS[0] + wsumS[1] + wsumS[2] + wsumS[3];
    }
}

// Kernel 4: sparse positive correction — ONE WAVE PER ROW (16384 waves).
// Lane l handles prior-range entry lo+l; binary search on the L2-resident
// per-batch sorted keys; duplicates in prior are skipped (isin semantics).
__global__ __launch_bounds__(256) void positives_kernel(
    const int* __restrict__ ids,
    const void* __restrict__ tf_raw,
    const void* __restrict__ act_raw,
    const int* __restrict__ prior,
    const float* __restrict__ u,
    const float* __restrict__ v,
    Ws* __restrict__ ws)
{
    __shared__ float wsumS[4];
    const int tid  = threadIdx.x;
    const int w    = tid >> 6;
    const int lane = tid & 63;
    const int row  = blockIdx.x * 4 + w;       // global row = (b, s) flat
    const int b    = row >> 11;
    const int bm   = ws->byteMode;

    float corr = 0.f;
    if (read_mask(tf_raw, row, bm)) {          // wave-uniform branch
        const int id = ids[row];
        const int lo = ws->bnd[id], hi = ws->bnd[id + 1];
        const unsigned int* skey = ws->sorted + b * SS;
        const float* urow = u + (size_t)row * DD;
        for (int m = lo + lane; m < hi; m += 64) {
            const int key = prior[m];
            if (m > lo && prior[m - 1] == key) continue;   // dedupe (isin)
            const unsigned int tgt = (unsigned int)(key - id * PAIR_BASE);
            const unsigned int target = tgt << 11;
            int l = 0, h = SS;
            while (l < h) {
                int mid = (l + h) >> 1;
                if (skey[mid] < target) l = mid + 1; else h = mid;
            }
            while (l < SS && (skey[l] >> 11) == tgt) {
                const int t = (int)(skey[l] & 2047u);
                if (read_mask(act_raw, b * SS + t, bm)) {
                    const float* vrow = v + (size_t)(b * SS + t) * DD;
                    float dot = 0.f;
                    #pragma unroll
                    for (int k2 = 0; k2 < DD; k2 += 4) {
                        float4 a = *(const float4*)(urow + k2);
                        float4 c = *(const float4*)(vrow + k2);
                        dot += (float)(__bf16)a.x * (float)(__bf16)c.x;
                        dot += (float)(__bf16)a.y * (float)(__bf16)c.y;
                        dot += (float)(__bf16)a.z * (float)(__bf16)c.z;
                        dot += (float)(__bf16)a.w * (float)(__bf16)c.w;
                    }
                    float p = fminf(fmaxf(dot, CEPS), 1.0f - CEPS);
                    float q = fminf(fmaxf(1.0f - dot, CEPS), 1.0f - CEPS);
                    corr += __logf(q) - __logf(p);
                }
                ++l;
            }
        }
    }
    #pragma unroll
    for (int o = 32; o > 0; o >>= 1)
        corr += __shfl_down(corr, o, 64);
    if (lane == 0) wsumS[w] = corr;
    __syncthreads();
    if (tid == 0)
        ws->ppart[blockIdx.x] = wsumS[0] + wsumS[1] + wsumS[2] + wsumS[3];
}

// Kernel 5: finalize — double-sum all partials + closed-form denominator.
__global__ __launch_bounds__(256) void finalize_kernel(const Ws* __restrict__ ws,
                                                       float* __restrict__ out) {
    __shared__ double sred[256];
    const int tid = threadIdx.x;
    double s = 0.0;
    for (int i = tid; i < MAIN_BLOCKS; i += 256) s += (double)ws->mpart[i];
    for (int i = tid; i < POS_BLOCKS;  i += 256) s += (double)ws->ppart[i];
    sred[tid] = s;
    __syncthreads();
    for (int o = 128; o > 0; o >>= 1) {
        if (tid < o) sred[tid] += sred[tid + o];
        __syncthreads();
    }
    if (tid == 0) {
        double denom = 0.0;
        for (int b = 0; b < BB; ++b)
            denom += (double)ws->tfc[b] * (double)ws->actc[b];
        out[0] = (float)(sred[0] / (denom + 1e-8));
    }
}

extern "C" void kernel_launch(void* const* d_in, const int* in_sizes, int n_in,
                              void* d_out, int out_size, void* d_ws, size_t ws_size,
                              hipStream_t stream) {
    (void)n_in; (void)out_size; (void)ws_size;
    const int*   ids   = (const int*)d_in[0];
    const void*  tf    = d_in[1];
    const void*  act   = d_in[2];
    const int*   prior = (const int*)d_in[3];
    const int    M     = in_sizes[3];
    const float* u     = (const float*)d_in[4];
    const float* v     = (const float*)d_in[5];
    Ws* ws = (Ws*)d_ws;
    float* out = (float*)d_out;

    init_kernel<<<1, 256, 0, stream>>>(tf, act, ws);
    bnd_kernel<<<(NBND + 255) / 256, 256, 0, stream>>>(prior, M, ws);
    sort_ids_kernel<<<BB, 1024, 0, stream>>>(ids, ws);
    dim3 grid(SS / 128, SS / 128, BB);
    prior_loss_main<<<grid, 256, 0, stream>>>(tf, act, u, v, ws);
    positives_kernel<<<POS_BLOCKS, 256, 0, stream>>>(ids, tf, act, prior, u, v, ws);
    finalize_kernel<<<1, 256, 0, stream>>>(ws, out);
}

// Round 5
// 147.890 us; speedup vs baseline: 6.2372x; 1.3121x over previous
//
#include <hip/hip_runtime.h>
#include <math.h>

#define BB 8
#define SS 2048
#define DD 64
#define PAIR_BASE 20000
#define CEPS 1e-8f
#define NROWS (BB * SS)
#define NBND (PAIR_BASE + 1)
#define MAIN_BLOCKS (16 * 16 * BB)   // 2048
#define POS_BLOCKS (NROWS / 4)       // 4096 (4 waves/block, 1 wave/row)

typedef __bf16 bf16x8 __attribute__((ext_vector_type(8)));
typedef __bf16 bf16x4 __attribute__((ext_vector_type(4)));
typedef float  f32x4  __attribute__((ext_vector_type(4)));

// Workspace (~170 KB): no global atomics anywhere — per-block partials.
struct Ws {
    int byteMode;
    int pad;
    float tfpart[BB * 16];          // per (b, y-slab) TF-row count (from main x==0)
    float actpart[BB * 16];         // per (b, x-slab) active-col count (from main y==0)
    int bnd[NBND];                  // lower_bound(prior, id*20000) per id
    unsigned int sorted[NROWS];     // per batch: (id<<11)|t, bitonic-sorted
    float mpart[MAIN_BLOCKS];       // main per-block negative-term sums
    float ppart[POS_BLOCKS];        // positives per-block corrections
};

__device__ __forceinline__ bool read_mask(const void* p, int i, int byteMode) {
    if (byteMode) return ((const unsigned char*)p)[i] != 0;
    return ((const int*)p)[i] != 0;
}

// Kernel 0 (prep, fused): blocks 0..7 bitonic-sort batch keys; blocks 8..27
// build the prior boundary table; block 28 detects mask dtype.
__global__ __launch_bounds__(1024) void prep_kernel(const int* __restrict__ ids,
                                                    const int* __restrict__ prior, int M,
                                                    const void* __restrict__ tf_raw,
                                                    Ws* __restrict__ ws) {
    __shared__ unsigned int arr[SS];
    const int blk = blockIdx.x;
    const int tid = threadIdx.x;

    if (blk < BB) {
        // ---- per-batch bitonic sort of (id<<11)|t ----
        const int b = blk;
        for (int i = tid; i < SS; i += 1024)
            arr[i] = ((unsigned int)ids[b * SS + i] << 11) | (unsigned int)i;
        __syncthreads();
        for (int k = 2; k <= SS; k <<= 1) {
            for (int j = k >> 1; j > 0; j >>= 1) {
                for (int t = tid; t < SS; t += 1024) {
                    int ixj = t ^ j;
                    if (ixj > t) {
                        unsigned int a = arr[t], c = arr[ixj];
                        bool up = ((t & k) == 0);
                        if ((a > c) == up) { arr[t] = c; arr[ixj] = a; }
                    }
                }
                __syncthreads();
            }
        }
        for (int i = tid; i < SS; i += 1024)
            ws->sorted[b * SS + i] = arr[i];
    } else if (blk < BB + 20) {
        // ---- bnd[id] = lower_bound(prior, id*20000) ----
        const int i = (blk - BB) * 1024 + tid;
        if (i < NBND) {
            const int x = i * PAIR_BASE;            // max 4.0e8 < INT_MAX
            int lo = 0, hi = M;
            while (lo < hi) {
                int mid = (lo + hi) >> 1;
                if (prior[mid] < x) lo = mid + 1; else hi = mid;
            }
            ws->bnd[i] = lo;
        }
    } else {
        // ---- mask dtype detection: 1024 words (4 KB, valid in both layouts).
        // byte-mode: P(word<=1) = 1/8 per word -> false-negative prob 8^-1024.
        __shared__ int bad;
        if (tid == 0) bad = 0;
        __syncthreads();
        const unsigned int* w = (const unsigned int*)tf_raw;
        if (w[tid] > 1u) atomicOr(&bad, 1);
        __syncthreads();
        if (tid == 0) ws->byteMode = bad;
    }
}

// Kernel 1: MFMA main, uniform negative-term sum (branchless epilogue).
// Edge blocks (x==0 / y==0) also emit per-slab mask counts for the
// closed-form denominator.
__global__ __launch_bounds__(256) void prior_loss_main(
    const void* __restrict__ tf_raw,
    const void* __restrict__ act_raw,
    const float* __restrict__ u,
    const float* __restrict__ v,
    Ws* __restrict__ ws)
{
    __shared__ __align__(16) __bf16 Ulds[128 * 72];
    __shared__ __align__(16) __bf16 Vlds[128 * 72];
    __shared__ float srow_tff[128];
    __shared__ float scol_actf[128];
    __shared__ float wsumS[4];

    const int b  = blockIdx.z;
    const int s0 = blockIdx.y * 128;
    const int t0 = blockIdx.x * 128;
    const int tid = threadIdx.x;
    const int byteMode = ws->byteMode;

    const float* ubase = u + ((size_t)(b * SS + s0)) * DD;
    const float* vbase = v + ((size_t)(b * SS + t0)) * DD;
    #pragma unroll
    for (int it = 0; it < 8; ++it) {
        int li = tid + it * 256;
        int r  = li >> 4;
        int c4 = li & 15;
        float4 fu = *(const float4*)(ubase + r * DD + c4 * 4);
        float4 fv = *(const float4*)(vbase + r * DD + c4 * 4);
        bf16x4 hu = { (__bf16)fu.x, (__bf16)fu.y, (__bf16)fu.z, (__bf16)fu.w };
        bf16x4 hv = { (__bf16)fv.x, (__bf16)fv.y, (__bf16)fv.z, (__bf16)fv.w };
        *(bf16x4*)&Ulds[r * 72 + c4 * 4] = hu;
        *(bf16x4*)&Vlds[r * 72 + c4 * 4] = hv;
    }
    if (tid < 128) {
        srow_tff[tid] = read_mask(tf_raw, b * SS + s0 + tid, byteMode) ? 1.f : 0.f;
    } else {
        int t = tid - 128;
        scol_actf[t] = read_mask(act_raw, b * SS + t0 + t, byteMode) ? 1.f : 0.f;
    }
    __syncthreads();

    const int w    = tid >> 6;
    const int lane = tid & 63;

    // ---- edge-block mask counting (denominator) ----
    if (blockIdx.x == 0 && w == 0) {
        float c = srow_tff[lane] + srow_tff[lane + 64];
        #pragma unroll
        for (int o = 32; o > 0; o >>= 1) c += __shfl_down(c, o, 64);
        if (lane == 0) ws->tfpart[b * 16 + blockIdx.y] = c;
    }
    if (blockIdx.y == 0 && w == 1) {
        float c = scol_actf[lane] + scol_actf[lane + 64];
        #pragma unroll
        for (int o = 32; o > 0; o >>= 1) c += __shfl_down(c, o, 64);
        if (lane == 0) ws->actpart[b * 16 + blockIdx.x] = c;
    }

    const int quad = lane >> 4;
    const int l15  = lane & 15;
    const int wm0  = (w >> 1) * 64;
    const int wn0  = (w & 1) * 64;

    f32x4 acc[4][4];
    #pragma unroll
    for (int i = 0; i < 4; ++i)
        #pragma unroll
        for (int j = 0; j < 4; ++j)
            acc[i][j] = (f32x4){0.f, 0.f, 0.f, 0.f};

    #pragma unroll
    for (int kh = 0; kh < 2; ++kh) {
        const int kcol = kh * 32 + quad * 8;
        bf16x8 af[4], bfr[4];
        #pragma unroll
        for (int ti = 0; ti < 4; ++ti)
            af[ti] = *(const bf16x8*)&Ulds[(wm0 + ti * 16 + l15) * 72 + kcol];
        #pragma unroll
        for (int tj = 0; tj < 4; ++tj)
            bfr[tj] = *(const bf16x8*)&Vlds[(wn0 + tj * 16 + l15) * 72 + kcol];
        #pragma unroll
        for (int ti = 0; ti < 4; ++ti)
            #pragma unroll
            for (int tj = 0; tj < 4; ++tj)
                acc[ti][tj] = __builtin_amdgcn_mfma_f32_16x16x32_bf16(
                    af[ti], bfr[tj], acc[ti][tj], 0, 0, 0);
    }

    // C/D layout: col = lane&15, row = quad*4 + reg.
    float actf4[4];
    #pragma unroll
    for (int tj = 0; tj < 4; ++tj) actf4[tj] = scol_actf[wn0 + tj * 16 + l15];

    float lsum = 0.f;
    #pragma unroll
    for (int ti = 0; ti < 4; ++ti) {
        #pragma unroll
        for (int r = 0; r < 4; ++r) {
            const int mloc = wm0 + ti * 16 + quad * 4 + r;
            const float tff = srow_tff[mloc];
            float rsum = 0.f;
            #pragma unroll
            for (int tj = 0; tj < 4; ++tj) {
                float q = 1.0f - acc[ti][tj][r];
                q = fminf(fmaxf(q, CEPS), 1.0f - CEPS);
                rsum += actf4[tj] * __logf(q);
            }
            lsum += tff * rsum;
        }
    }
    lsum = -lsum;

    #pragma unroll
    for (int o = 32; o > 0; o >>= 1)
        lsum += __shfl_down(lsum, o, 64);
    if (lane == 0) wsumS[w] = lsum;
    __syncthreads();
    if (tid == 0) {
        const int flat = (blockIdx.z * gridDim.y + blockIdx.y) * gridDim.x + blockIdx.x;
        ws->mpart[flat] = wsumS[0] + wsumS[1] + wsumS[2] + wsumS[3];
    }
}

// Kernel 2: sparse positive correction — one wave per row (16384 waves).
__global__ __launch_bounds__(256) void positives_kernel(
    const int* __restrict__ ids,
    const void* __restrict__ tf_raw,
    const void* __restrict__ act_raw,
    const int* __restrict__ prior,
    const float* __restrict__ u,
    const float* __restrict__ v,
    Ws* __restrict__ ws)
{
    __shared__ float wsumS[4];
    const int tid  = threadIdx.x;
    const int w    = tid >> 6;
    const int lane = tid & 63;
    const int row  = blockIdx.x * 4 + w;       // global row = (b, s) flat
    const int b    = row >> 11;
    const int bm   = ws->byteMode;

    float corr = 0.f;
    if (read_mask(tf_raw, row, bm)) {          // wave-uniform branch
        const int id = ids[row];
        const int lo = ws->bnd[id], hi = ws->bnd[id + 1];
        const unsigned int* skey = ws->sorted + b * SS;
        const float* urow = u + (size_t)row * DD;
        for (int m = lo + lane; m < hi; m += 64) {
            const int key = prior[m];
            if (m > lo && prior[m - 1] == key) continue;   // dedupe (isin)
            const unsigned int tgt = (unsigned int)(key - id * PAIR_BASE);
            const unsigned int target = tgt << 11;
            int l = 0, h = SS;
            while (l < h) {
                int mid = (l + h) >> 1;
                if (skey[mid] < target) l = mid + 1; else h = mid;
            }
            while (l < SS && (skey[l] >> 11) == tgt) {
                const int t = (int)(skey[l] & 2047u);
                if (read_mask(act_raw, b * SS + t, bm)) {
                    const float* vrow = v + (size_t)(b * SS + t) * DD;
                    float dot = 0.f;
                    #pragma unroll
                    for (int k2 = 0; k2 < DD; k2 += 4) {
                        float4 a = *(const float4*)(urow + k2);
                        float4 c = *(const float4*)(vrow + k2);
                        dot += (float)(__bf16)a.x * (float)(__bf16)c.x;
                        dot += (float)(__bf16)a.y * (float)(__bf16)c.y;
                        dot += (float)(__bf16)a.z * (float)(__bf16)c.z;
                        dot += (float)(__bf16)a.w * (float)(__bf16)c.w;
                    }
                    float p = fminf(fmaxf(dot, CEPS), 1.0f - CEPS);
                    float q = fminf(fmaxf(1.0f - dot, CEPS), 1.0f - CEPS);
                    corr += __logf(q) - __logf(p);
                }
                ++l;
            }
        }
    }
    #pragma unroll
    for (int o = 32; o > 0; o >>= 1)
        corr += __shfl_down(corr, o, 64);
    if (lane == 0) wsumS[w] = corr;
    __syncthreads();
    if (tid == 0)
        ws->ppart[blockIdx.x] = wsumS[0] + wsumS[1] + wsumS[2] + wsumS[3];
}

// Kernel 3: finalize — double-sum partials + closed-form denominator.
__global__ __launch_bounds__(256) void finalize_kernel(const Ws* __restrict__ ws,
                                                       float* __restrict__ out) {
    __shared__ double sred[256];
    const int tid = threadIdx.x;
    double s = 0.0;
    for (int i = tid; i < MAIN_BLOCKS; i += 256) s += (double)ws->mpart[i];
    for (int i = tid; i < POS_BLOCKS;  i += 256) s += (double)ws->ppart[i];
    sred[tid] = s;
    __syncthreads();
    for (int o = 128; o > 0; o >>= 1) {
        if (tid < o) sred[tid] += sred[tid + o];
        __syncthreads();
    }
    if (tid == 0) {
        double denom = 0.0;
        for (int b = 0; b < BB; ++b) {
            double tfc = 0.0, acc = 0.0;
            for (int k = 0; k < 16; ++k) {
                tfc += (double)ws->tfpart[b * 16 + k];
                acc += (double)ws->actpart[b * 16 + k];
            }
            denom += tfc * acc;
        }
        out[0] = (float)(sred[0] / (denom + 1e-8));
    }
}

extern "C" void kernel_launch(void* const* d_in, const int* in_sizes, int n_in,
                              void* d_out, int out_size, void* d_ws, size_t ws_size,
                              hipStream_t stream) {
    (void)n_in; (void)out_size; (void)ws_size;
    const int*   ids   = (const int*)d_in[0];
    const void*  tf    = d_in[1];
    const void*  act   = d_in[2];
    const int*   prior = (const int*)d_in[3];
    const int    M     = in_sizes[3];
    const float* u     = (const float*)d_in[4];
    const float* v     = (const float*)d_in[5];
    Ws* ws = (Ws*)d_ws;
    float* out = (float*)d_out;

    prep_kernel<<<BB + 20 + 1, 1024, 0, stream>>>(ids, prior, M, tf, ws);
    dim3 grid(SS / 128, SS / 128, BB);
    prior_loss_main<<<grid, 256, 0, stream>>>(tf, act, u, v, ws);
    positives_kernel<<<POS_BLOCKS, 256, 0, stream>>>(ids, tf, act, prior, u, v, ws);
    finalize_kernel<<<1, 256, 0, stream>>>(ws, out);
}

// Round 6
// 137.284 us; speedup vs baseline: 6.7191x; 1.0773x over previous
//
#include <hip/hip_runtime.h>
#include <math.h>

#define BB 8
#define SS 2048
#define DD 64
#define PAIR_BASE 20000
#define CEPS 1e-8f
#define NROWS (BB * SS)
#define NBND (PAIR_BASE + 1)
#define MAIN_BLOCKS (16 * 16 * BB)   // worst-case grid; most blocks early-exit
#define POS_BLOCKS (NROWS / 4)       // 4096 (4 waves/block, 1 wave/row)
#define PREP_CMP (BB + 21)           // compact blocks start here
#define PREP_BLOCKS (BB + 21 + BB)   // 8 sort + 20 bnd + 1 detect + 8 compact

typedef __bf16 bf16x8 __attribute__((ext_vector_type(8)));
typedef __bf16 bf16x4 __attribute__((ext_vector_type(4)));
typedef float  f32x4  __attribute__((ext_vector_type(4)));

// Workspace (~4.4 MB): per-block partials only, no global atomics.
struct Ws {
    int byteMode;
    int pad;
    int mc[BB];                     // compacted TF-row count per batch
    int nc[BB];                     // compacted active-col count per batch
    int bnd[NBND];                  // lower_bound(prior, id*20000) per id
    unsigned int sorted[NROWS];     // per batch: (id<<11)|t, bitonic-sorted
    float mpart[MAIN_BLOCKS];       // main per-block negative-term sums
    float ppart[POS_BLOCKS];        // positives per-block corrections
    __bf16 Uc[(size_t)BB * SS * DD];  // compacted TF rows of u (bf16, zero-padded)
    __bf16 Vc[(size_t)BB * SS * DD];  // compacted active rows of v
};

__device__ __forceinline__ bool read_mask(const void* p, int i, int byteMode) {
    if (byteMode) return ((const unsigned char*)p)[i] != 0;
    return ((const int*)p)[i] != 0;
}

// Kernel 0 (prep, fused; 37 blocks x 1024):
//   blocks 0..7   : per-batch bitonic sort of (id<<11)|t
//   blocks 8..27  : prior boundary table bnd[]
//   block  28     : mask-dtype detect -> ws->byteMode (used by positives)
//   blocks 29..36 : per-batch mask scan + compaction gather of u,v -> Uc,Vc
__global__ __launch_bounds__(1024) void prep_kernel(
    const int* __restrict__ ids,
    const int* __restrict__ prior, int M,
    const void* __restrict__ tf_raw,
    const void* __restrict__ act_raw,
    const float* __restrict__ u,
    const float* __restrict__ v,
    Ws* __restrict__ ws)
{
    __shared__ unsigned int arr[SS];
    __shared__ int ssum[1024];
    __shared__ unsigned short cidx[SS];
    __shared__ int stot;
    __shared__ int badl;

    const int blk = blockIdx.x;
    const int tid = threadIdx.x;

    if (blk < BB) {
        // ---- per-batch bitonic sort ----
        const int b = blk;
        for (int i = tid; i < SS; i += 1024)
            arr[i] = ((unsigned int)ids[b * SS + i] << 11) | (unsigned int)i;
        __syncthreads();
        for (int k = 2; k <= SS; k <<= 1) {
            for (int j = k >> 1; j > 0; j >>= 1) {
                for (int t = tid; t < SS; t += 1024) {
                    int ixj = t ^ j;
                    if (ixj > t) {
                        unsigned int a = arr[t], c = arr[ixj];
                        bool up = ((t & k) == 0);
                        if ((a > c) == up) { arr[t] = c; arr[ixj] = a; }
                    }
                }
                __syncthreads();
            }
        }
        for (int i = tid; i < SS; i += 1024)
            ws->sorted[b * SS + i] = arr[i];
    } else if (blk < BB + 20) {
        // ---- bnd[id] = lower_bound(prior, id*20000) ----
        const int i = (blk - BB) * 1024 + tid;
        if (i < NBND) {
            const int x = i * PAIR_BASE;            // max 4.0e8 < INT_MAX
            int lo = 0, hi = M;
            while (lo < hi) {
                int mid = (lo + hi) >> 1;
                if (prior[mid] < x) lo = mid + 1; else hi = mid;
            }
            ws->bnd[i] = lo;
        }
    } else if (blk < PREP_CMP) {
        // ---- mask dtype detect (4 KB; false-negative prob 8^-1024) ----
        if (tid == 0) badl = 0;
        __syncthreads();
        if (((const unsigned int*)tf_raw)[tid] > 1u) atomicOr(&badl, 1);
        __syncthreads();
        if (tid == 0) ws->byteMode = badl;
    } else {
        // ---- per-batch compaction: scan masks, gather bf16 rows, zero-pad ----
        const int b = blk - PREP_CMP;
        if (tid == 0) badl = 0;
        __syncthreads();
        if (((const unsigned int*)tf_raw)[tid] > 1u) atomicOr(&badl, 1);
        __syncthreads();
        const int bm = badl;

        for (int phase = 0; phase < 2; ++phase) {
            const void* mraw = phase ? act_raw : tf_raw;
            const int e0 = b * SS + 2 * tid;
            const int m0 = read_mask(mraw, e0,     bm) ? 1 : 0;
            const int m1 = read_mask(mraw, e0 + 1, bm) ? 1 : 0;
            ssum[tid] = m0 + m1;
            __syncthreads();
            // Hillis-Steele inclusive scan over 1024 thread-sums
            for (int o = 1; o < 1024; o <<= 1) {
                int val = ssum[tid];
                if (tid >= o) val += ssum[tid - o];
                __syncthreads();
                ssum[tid] = val;
                __syncthreads();
            }
            const int incl = ssum[tid];
            const int excl = incl - m0 - m1;
            if (m0) cidx[excl]      = (unsigned short)(2 * tid);
            if (m1) cidx[excl + m0] = (unsigned short)(2 * tid + 1);
            if (tid == 1023) stot = incl;
            __syncthreads();
            const int total = stot;
            if (tid == 0) { if (phase) ws->nc[b] = total; else ws->mc[b] = total; }
            const int tpad = (total + 127) & ~127;
            __bf16* dst = (phase ? ws->Vc : ws->Uc) + (size_t)b * SS * DD;
            const float* src = (phase ? v : u) + (size_t)b * SS * DD;
            const int r_off = tid >> 4, c = tid & 15;   // 16 threads/row
            for (int r0 = 0; r0 < tpad; r0 += 64) {
                const int r = r0 + r_off;
                if (r < tpad) {
                    bf16x4 hv;
                    if (r < total) {
                        const float4 f = *(const float4*)(src + (size_t)cidx[r] * DD + c * 4);
                        hv = (bf16x4){ (__bf16)f.x, (__bf16)f.y, (__bf16)f.z, (__bf16)f.w };
                    } else {
                        hv = (bf16x4){ (__bf16)0.f, (__bf16)0.f, (__bf16)0.f, (__bf16)0.f };
                    }
                    *(bf16x4*)(dst + (size_t)r * DD + c * 4) = hv;
                }
            }
            __syncthreads();   // before next phase reuses ssum/cidx
        }
    }
}

// Kernel 1: compacted MFMA main.  All pairs are supervised; pad rows/cols
// contribute exactly 0 (dot=0 -> q=1.0f -> log=0).  Mask-free epilogue.
__global__ __launch_bounds__(256) void prior_loss_main(Ws* __restrict__ ws)
{
    const int b  = blockIdx.z;
    const int s0 = blockIdx.y * 128;
    const int t0 = blockIdx.x * 128;
    const int tid = threadIdx.x;
    const int flat = (blockIdx.z * gridDim.y + blockIdx.y) * gridDim.x + blockIdx.x;

    const int mcp = (ws->mc[b] + 127) & ~127;
    const int ncp = (ws->nc[b] + 127) & ~127;
    if (s0 >= mcp || t0 >= ncp) {
        if (tid == 0) ws->mpart[flat] = 0.f;
        return;
    }

    __shared__ __align__(16) __bf16 Ulds[128 * 72];
    __shared__ __align__(16) __bf16 Vlds[128 * 72];
    __shared__ float wsumS[4];

    const __bf16* ub = ws->Uc + (size_t)(b * SS + s0) * DD;
    const __bf16* vb = ws->Vc + (size_t)(b * SS + t0) * DD;
    #pragma unroll
    for (int it = 0; it < 4; ++it) {
        int li = tid + it * 256;        // 0..1023: 128 rows x 8 chunks of 8 bf16
        int r  = li >> 3;
        int c8 = li & 7;
        *(bf16x8*)&Ulds[r * 72 + c8 * 8] = *(const bf16x8*)(ub + r * DD + c8 * 8);
        *(bf16x8*)&Vlds[r * 72 + c8 * 8] = *(const bf16x8*)(vb + r * DD + c8 * 8);
    }
    __syncthreads();

    const int w    = tid >> 6;
    const int lane = tid & 63;
    const int quad = lane >> 4;
    const int l15  = lane & 15;
    const int wm0  = (w >> 1) * 64;
    const int wn0  = (w & 1) * 64;

    f32x4 acc[4][4];
    #pragma unroll
    for (int i = 0; i < 4; ++i)
        #pragma unroll
        for (int j = 0; j < 4; ++j)
            acc[i][j] = (f32x4){0.f, 0.f, 0.f, 0.f};

    #pragma unroll
    for (int kh = 0; kh < 2; ++kh) {
        const int kcol = kh * 32 + quad * 8;
        bf16x8 af[4], bfr[4];
        #pragma unroll
        for (int ti = 0; ti < 4; ++ti)
            af[ti] = *(const bf16x8*)&Ulds[(wm0 + ti * 16 + l15) * 72 + kcol];
        #pragma unroll
        for (int tj = 0; tj < 4; ++tj)
            bfr[tj] = *(const bf16x8*)&Vlds[(wn0 + tj * 16 + l15) * 72 + kcol];
        #pragma unroll
        for (int ti = 0; ti < 4; ++ti)
            #pragma unroll
            for (int tj = 0; tj < 4; ++tj)
                acc[ti][tj] = __builtin_amdgcn_mfma_f32_16x16x32_bf16(
                    af[ti], bfr[tj], acc[ti][tj], 0, 0, 0);
    }

    // Mask-free epilogue.  C/D layout: col = lane&15, row = quad*4 + reg.
    float lsum = 0.f;
    #pragma unroll
    for (int ti = 0; ti < 4; ++ti)
        #pragma unroll
        for (int r = 0; r < 4; ++r)
            #pragma unroll
            for (int tj = 0; tj < 4; ++tj) {
                float q = 1.0f - acc[ti][tj][r];
                q = fminf(fmaxf(q, CEPS), 1.0f - CEPS);
                lsum += __logf(q);
            }
    lsum = -lsum;

    #pragma unroll
    for (int o = 32; o > 0; o >>= 1)
        lsum += __shfl_down(lsum, o, 64);
    if (lane == 0) wsumS[w] = lsum;
    __syncthreads();
    if (tid == 0)
        ws->mpart[flat] = wsumS[0] + wsumS[1] + wsumS[2] + wsumS[3];
}

// Kernel 2: sparse positive correction — one wave per row (16384 waves).
__global__ __launch_bounds__(256) void positives_kernel(
    const int* __restrict__ ids,
    const void* __restrict__ tf_raw,
    const void* __restrict__ act_raw,
    const int* __restrict__ prior,
    const float* __restrict__ u,
    const float* __restrict__ v,
    Ws* __restrict__ ws)
{
    __shared__ float wsumS[4];
    const int tid  = threadIdx.x;
    const int w    = tid >> 6;
    const int lane = tid & 63;
    const int row  = blockIdx.x * 4 + w;       // global row = (b, s) flat
    const int b    = row >> 11;
    const int bm   = ws->byteMode;

    float corr = 0.f;
    if (read_mask(tf_raw, row, bm)) {          // wave-uniform branch
        const int id = ids[row];
        const int lo = ws->bnd[id], hi = ws->bnd[id + 1];
        const unsigned int* skey = ws->sorted + b * SS;
        const float* urow = u + (size_t)row * DD;
        for (int m = lo + lane; m < hi; m += 64) {
            const int key = prior[m];
            if (m > lo && prior[m - 1] == key) continue;   // dedupe (isin)
            const unsigned int tgt = (unsigned int)(key - id * PAIR_BASE);
            const unsigned int target = tgt << 11;
            int l = 0, h = SS;
            while (l < h) {
                int mid = (l + h) >> 1;
                if (skey[mid] < target) l = mid + 1; else h = mid;
            }
            while (l < SS && (skey[l] >> 11) == tgt) {
                const int t = (int)(skey[l] & 2047u);
                if (read_mask(act_raw, b * SS + t, bm)) {
                    const float* vrow = v + (size_t)(b * SS + t) * DD;
                    float dot = 0.f;
                    #pragma unroll
                    for (int k2 = 0; k2 < DD; k2 += 4) {
                        float4 a = *(const float4*)(urow + k2);
                        float4 c = *(const float4*)(vrow + k2);
                        dot += (float)(__bf16)a.x * (float)(__bf16)c.x;
                        dot += (float)(__bf16)a.y * (float)(__bf16)c.y;
                        dot += (float)(__bf16)a.z * (float)(__bf16)c.z;
                        dot += (float)(__bf16)a.w * (float)(__bf16)c.w;
                    }
                    float p = fminf(fmaxf(dot, CEPS), 1.0f - CEPS);
                    float q = fminf(fmaxf(1.0f - dot, CEPS), 1.0f - CEPS);
                    corr += __logf(q) - __logf(p);
                }
                ++l;
            }
        }
    }
    #pragma unroll
    for (int o = 32; o > 0; o >>= 1)
        corr += __shfl_down(corr, o, 64);
    if (lane == 0) wsumS[w] = corr;
    __syncthreads();
    if (tid == 0)
        ws->ppart[blockIdx.x] = wsumS[0] + wsumS[1] + wsumS[2] + wsumS[3];
}

// Kernel 3: finalize — double-sum partials + closed-form denominator.
__global__ __launch_bounds__(256) void finalize_kernel(const Ws* __restrict__ ws,
                                                       float* __restrict__ out) {
    __shared__ double sred[256];
    const int tid = threadIdx.x;
    double s = 0.0;
    for (int i = tid; i < MAIN_BLOCKS; i += 256) s += (double)ws->mpart[i];
    for (int i = tid; i < POS_BLOCKS;  i += 256) s += (double)ws->ppart[i];
    sred[tid] = s;
    __syncthreads();
    for (int o = 128; o > 0; o >>= 1) {
        if (tid < o) sred[tid] += sred[tid + o];
        __syncthreads();
    }
    if (tid == 0) {
        double denom = 0.0;
        for (int b = 0; b < BB; ++b)
            denom += (double)ws->mc[b] * (double)ws->nc[b];
        out[0] = (float)(sred[0] / (denom + 1e-8));
    }
}

extern "C" void kernel_launch(void* const* d_in, const int* in_sizes, int n_in,
                              void* d_out, int out_size, void* d_ws, size_t ws_size,
                              hipStream_t stream) {
    (void)n_in; (void)out_size; (void)ws_size;
    const int*   ids   = (const int*)d_in[0];
    const void*  tf    = d_in[1];
    const void*  act   = d_in[2];
    const int*   prior = (const int*)d_in[3];
    const int    M     = in_sizes[3];
    const float* u     = (const float*)d_in[4];
    const float* v     = (const float*)d_in[5];
    Ws* ws = (Ws*)d_ws;
    float* out = (float*)d_out;

    prep_kernel<<<PREP_BLOCKS, 1024, 0, stream>>>(ids, prior, M, tf, act, u, v, ws);
    dim3 grid(SS / 128, SS / 128, BB);
    prior_loss_main<<<grid, 256, 0, stream>>>(ws);
    positives_kernel<<<POS_BLOCKS, 256, 0, stream>>>(ids, tf, act, prior, u, v, ws);
    finalize_kernel<<<1, 256, 0, stream>>>(ws, out);
}